// Round 14
// baseline (480.563 us; speedup 1.0000x reference)
//
#include <hip/hip_runtime.h>
#include <math.h>

typedef unsigned long long u64;

static constexpr int S    = 771;   // NB_LABELS*MAX_DEPTH + EXTRA
static constexpr int Tn   = 128;
static constexpr int Bn   = 32;
static constexpr int BOSs = 0;
static constexpr int EOSs = 1;

static constexpr int JPAD  = 832;          // 13 * 64 state pad
static constexpr int JB    = 13;           // state-blocks per batch
static constexpr int ROWS  = 64;           // output rows per block (= lanes)
static constexpr int NQ    = 4;            // inner K-quarters (= waves)
static constexpr int SL    = JPAD / NQ;    // 208 i8 inner slice per thread
static constexpr int CH    = SL / 16;      // 13 x b128 per thread
static constexpr int EBLK  = NQ * CH * ROWS * 16;    // 53248 B per jblk
static constexpr int ETOT  = JB * EBLK;              // 692224 B
static constexpr int NPUB  = 16;           // u64 per publisher (max embedded)
static constexpr int XSTR  = 224;          // stride (u64) per (parity,batch)
static constexpr unsigned TAGB = 0x5A00u;  // tag16 = 0x5A00|t; poison=0xAAAA
static constexpr float CB  = 8.0f;         // normalizer headroom (drift bound)
static constexpr float C0V = 4.5f;         // fixed normalizer for t=0 publish

__device__ __forceinline__ float wave_max_bfly(float v) {   // result in ALL lanes
    #pragma unroll
    for (int off = 32; off > 0; off >>= 1) v = fmaxf(v, __shfl_xor(v, off));
    return v;
}
__device__ __forceinline__ float wave_sum_f(float v) {
    #pragma unroll
    for (int off = 32; off > 0; off >>= 1) v += __shfl_down(v, off);
    return v;
}

union HU16 { _Float16 h; unsigned short u; };

// MALL-scope (agent atomic) exchange: the r4-r13 replay-proven protocol.
__device__ __forceinline__ u64 ald64(const u64* p) {
    return __hip_atomic_load((u64*)p, __ATOMIC_RELAXED, __HIP_MEMORY_SCOPE_AGENT);
}
__device__ __forceinline__ void ast64(u64* p, u64 v) {
    __hip_atomic_store(p, v, __ATOMIC_RELAXED, __HIP_MEMORY_SCOPE_AGENT);
}

// i8 x i8 + i32 dot (both operands in [0,127], so signed == unsigned)
#if __has_builtin(__builtin_amdgcn_sdot4)
__device__ __forceinline__ int dot4i(unsigned a, unsigned b, int c) {
    return __builtin_amdgcn_sdot4((int)a, (int)b, c, false);
}
#else
__device__ __forceinline__ int dot4i(unsigned a, unsigned b, int c) {
    c += (int)(a & 0xff)         * (int)(b & 0xff);
    c += (int)((a >> 8) & 0xff)  * (int)((b >> 8) & 0xff);
    c += (int)((a >> 16) & 0xff) * (int)((b >> 16) & 0xff);
    c += (int)((a >> 24) & 0xff) * (int)((b >> 24) & 0xff);
    return c;
}
#endif

// ---------------------------------------------------------------------------
// Prep: i8 exp-transition table (swizzled, layout unchanged since r8) +
// exp(trans[:,EOS]) f32 column.
// ---------------------------------------------------------------------------
extern "C" __global__ void build_tabs(const float* __restrict__ trans,
                                      unsigned char* __restrict__ eswz,
                                      float* __restrict__ eteos) {
    int idx = blockIdx.x * blockDim.x + threadIdx.x;
    if (idx < JPAD)
        eteos[idx] = (idx < S) ? __expf(trans[idx * S + EOSs]) : 0.f;
    if (idx >= ETOT) return;
    int e = idx & 15;
    int q = idx >> 4;
    int lane = q & 63;  q >>= 6;
    int kk = q % 13;
    int h  = q / 13;
    int w  = h & 3, jblk = h >> 2;
    int i = w * SL + kk * 16 + e;
    int j = jblk * ROWS + lane;
    float v = 0.f;
    if (i < S && j < S) v = 115.f * __expf(trans[i * S + j]);
    int q8 = (int)(v + 0.5f);
    if (q8 > 127) q8 = 127;
    eswz[idx] = (unsigned char)q8;
}

// publish (one wave): 64 rows -> 16 tagged u64, each carrying
// [tag16 | chunkmax_f16 | 4 x p8], p8 = round(127*exp(alpha-C)).
__device__ __forceinline__ void publish(u64* base, unsigned tg, float af,
                                        float C, int lane) {
    float xf = fminf(127.f, 127.f * __expf(af - C));   // -inf/-1e9 -> 0
    int xi = (int)(xf + 0.5f);
    int c0 = __shfl(xi, (4 * lane) & 63);
    int c1 = __shfl(xi, (4 * lane + 1) & 63);
    int c2 = __shfl(xi, (4 * lane + 2) & 63);
    int c3 = __shfl(xi, (4 * lane + 3) & 63);
    unsigned payload = (unsigned)c0 | ((unsigned)c1 << 8)
                     | ((unsigned)c2 << 16) | ((unsigned)c3 << 24);
    float mc = wave_max_bfly(af);
    HU16 hh; hh.h = (_Float16)mc;
    u64 v = ((u64)tg << 48) | ((u64)hh.u << 32) | (u64)payload;
    if (lane < NPUB) ast64(base + lane, v);
}

// ---------------------------------------------------------------------------
// Forward algorithm, r14 = r13 + CROSS-PHASE POLL PREFETCH.
// r13 accounting: phase = poll-load RT (~1300 cy, data already visible) +
// compute (~2200). The publish RT is hidden by the 2-batch interleave; the
// poll load's own MALL round trip is not. Fix: sample each phase's mailbox
// words ONE PHASE EARLY (phase B's words at phase A top; next step's phase A
// words at phase B top). Tag check decides: hit -> no global load at all in
// the phase (prefetch for the next phase stays outstanding, since nothing
// forces a vmcnt drain before the publish); stale -> the r13 spin loop runs
// unchanged. Pure sampling optimization -- protocol and safety untouched.
// ---------------------------------------------------------------------------
extern "C" __global__ __launch_bounds__(256, 2)
void crf_fwd(const float* __restrict__ em, const float* __restrict__ mask,
             const float* __restrict__ trans, const int* __restrict__ tags,
             const unsigned char* __restrict__ eswz,
             const float* __restrict__ eteos,
             u64* __restrict__ xb, float* __restrict__ out) {
    const int jblk = blockIdx.x;
    const int b0 = blockIdx.y * 2, b1 = b0 + 1;
    const int tid = threadIdx.x, lane = tid & 63, w = tid >> 6;
    const int j0 = jblk * ROWS;
    const int bw = (13 * w) / 4;             // first publisher of my K-quarter
    const int lo = 52 * w - 16 * bw;         // lane offset of my strip
    const int doff = NPUB * (bw + (lane >> 4)) + (lane & 15);  // my poll word

    __shared__ __align__(16) unsigned char Elds[EBLK];  // 52 KB i8 E tile
    __shared__ __align__(16) unsigned pq[2][NQ][52];    // per-phase wave strips
    __shared__ int   part[2][NQ][ROWS];
    __shared__ float wmax[2][NQ];
    __shared__ float csh[2];
    __shared__ float lz[2][4];
    __shared__ float redv[4], redm[4];

    const float KLOG  = __logf(115.f * 127.f);
    const float KL127 = __logf(127.f);

    // ---- one-time: stage this block's E tile (13 x 4KB linear copy) ----
    {
        const unsigned char* gsrc = eswz + (size_t)jblk * EBLK;
        #pragma unroll
        for (int it = 0; it < EBLK / 4096; ++it)
            *(float4*)(Elds + it * 4096 + tid * 16) =
                *(const float4*)(gsrc + it * 4096 + tid * 16);
    }

    // epilogue waves 0/1 own batches b0/b1: alpha of row j0+lane + normalizer
    const int myb = (w == 1) ? b1 : b0;
    float af = -INFINITY, Cuse = C0V;
    if (w < 2) {
        int j = j0 + lane;
        if (j < S) af = trans[BOSs * S + j] + em[((size_t)myb * Tn + 0) * S + j];
        publish(xb + ((size_t)0 * Bn + myb) * XSTR + NPUB * jblk,
                TAGB | 0u, af, C0V, lane);
    }

    // prologue prefetch: phase A (batch b0) gen-0 words, parity 0
    u64 qa = ald64(xb + ((size_t)0 * Bn + b0) * XSTR + doff);

    // ---- 127 sequential steps, 2 prefetch-pipelined phases each ----
    for (int t = 1; t < Tn; ++t) {
        const unsigned tgp = TAGB | (unsigned)(t - 1);
        const unsigned tgc = TAGB | (unsigned)t;
        const size_t roP = (size_t)((t - 1) & 1) * Bn;   // read-parity base

        // prefetch phase B's words NOW (published a full step ago -> visible)
        u64 qb = ald64(xb + (roP + b1) * XSTR + doff);

        // epilogue operands (waves 0/1 -> own batch), issued before any spin
        float emv = 0.f, mval = 0.f;
        if (w < 2) {
            const int j = j0 + lane;
            if (j < S) emv = em[((size_t)myb * Tn + t) * S + j];
            mval = mask[myb * Tn + t];
        }

        // ================= phase A : batch b0 =================
        {
            const u64* pd = xb + (roP + b0) * XSTR + doff;
            bool ok = ((unsigned)(qa >> 48) == tgp);     // prefetched sample
            while (__any(!ok)) {
                if (!ok) { qa = ald64(pd); ok = ((unsigned)(qa >> 48) == tgp); }
            }
            if (lane >= lo && lane < lo + 52) pq[0][w][lane - lo] = (unsigned)qa;
            HU16 hm; hm.u = (unsigned short)(qa >> 32);
            float wm = wave_max_bfly((float)hm.h);
            if (lane == 0) wmax[0][w] = wm;

            int acc = 0;
            const uint4* E4 = (const uint4*)Elds;
            const uint4* P4 = (const uint4*)pq[0][w];
            #pragma unroll
            for (int kk = 0; kk < CH; ++kk) {
                const uint4 ev = E4[(w * CH + kk) * 64 + lane];
                const uint4 pv = P4[kk];
                acc = dot4i(ev.x, pv.x, acc); acc = dot4i(ev.y, pv.y, acc);
                acc = dot4i(ev.z, pv.z, acc); acc = dot4i(ev.w, pv.w, acc);
            }
            part[0][w][lane] = acc;
            __syncthreads();
            if (w == 0) {   // waves 1-3 head into phase B immediately
                int s4 = part[0][0][lane] + part[0][1][lane]
                       + part[0][2][lane] + part[0][3][lane];
                float Cnew = fmaxf(fmaxf(wmax[0][0], wmax[0][1]),
                                   fmaxf(wmax[0][2], wmax[0][3])) + CB;
                float nv = Cuse - KLOG + __logf((float)s4) + emv;
                af = (mval > 0.f) ? nv : af;
                publish(xb + ((size_t)(t & 1) * Bn + b0) * XSTR + NPUB * jblk,
                        tgc, af, Cnew, lane);
                Cuse = Cnew;
            }
        }

        // prefetch next step's phase A words (batch b0, gen t, parity t&1).
        // Remote gen-t publishes happened ~now (their phase A end); by the
        // time this sample is checked (next iteration's phase A, one full
        // phase later) it is usually visible; stale -> spin handles it.
        u64 qan = 0;
        if (t < Tn - 1)
            qan = ald64(xb + ((size_t)(t & 1) * Bn + b0) * XSTR + doff);

        // ================= phase B : batch b1 =================
        {
            const u64* pd = xb + (roP + b1) * XSTR + doff;
            bool ok = ((unsigned)(qb >> 48) == tgp);     // prefetched sample
            while (__any(!ok)) {
                if (!ok) { qb = ald64(pd); ok = ((unsigned)(qb >> 48) == tgp); }
            }
            if (lane >= lo && lane < lo + 52) pq[1][w][lane - lo] = (unsigned)qb;
            HU16 hm; hm.u = (unsigned short)(qb >> 32);
            float wm = wave_max_bfly((float)hm.h);
            if (lane == 0) wmax[1][w] = wm;

            int acc = 0;
            const uint4* E4 = (const uint4*)Elds;
            const uint4* P4 = (const uint4*)pq[1][w];
            #pragma unroll
            for (int kk = 0; kk < CH; ++kk) {
                const uint4 ev = E4[(w * CH + kk) * 64 + lane];
                const uint4 pv = P4[kk];
                acc = dot4i(ev.x, pv.x, acc); acc = dot4i(ev.y, pv.y, acc);
                acc = dot4i(ev.z, pv.z, acc); acc = dot4i(ev.w, pv.w, acc);
            }
            part[1][w][lane] = acc;
            __syncthreads();
            if (w == 1) {   // other waves proceed to t+1 phase A
                int s4 = part[1][0][lane] + part[1][1][lane]
                       + part[1][2][lane] + part[1][3][lane];
                float Cnew = fmaxf(fmaxf(wmax[1][0], wmax[1][1]),
                                   fmaxf(wmax[1][2], wmax[1][3])) + CB;
                float nv = Cuse - KLOG + __logf((float)s4) + emv;
                af = (mval > 0.f) ? nv : af;
                publish(xb + ((size_t)(t & 1) * Bn + b1) * XSTR + NPUB * jblk,
                        tgc, af, Cnew, lane);
                Cuse = Cnew;
            }
        }
        qa = qan;
    }

    // ---- tail (blocks jblk==0): log_Z + gold scores for both batches ----
    if (jblk == 0) {
        if (w < 2 && lane == 0) csh[w] = Cuse;   // C of gen-127 publish
        const unsigned tgf = TAGB | (unsigned)(Tn - 1);
        const u64* RA = xb + ((size_t)((Tn - 1) & 1) * Bn + b0) * XSTR;
        const u64* RB = xb + ((size_t)((Tn - 1) & 1) * Bn + b1) * XSTR;
        const bool actp = (tid < JB * NPUB);     // 208 slots
        u64 qA = 0, qB = 0;
        bool oka = !actp, okb = !actp;
        while (true) {
            if (!oka) { qA = ald64(RA + tid); oka = ((unsigned)(qA >> 48) == tgf); }
            if (!okb) { qB = ald64(RB + tid); okb = ((unsigned)(qB >> 48) == tgf); }
            if (__syncthreads_and(oka & okb)) break;
        }
        float lA = 0.f, lB = 0.f;
        if (actp) {
            unsigned pa = (unsigned)qA, pb = (unsigned)qB;
            int base = 4 * tid;
            lA = (float)(pa & 0xff)         * eteos[base]
               + (float)((pa >> 8)  & 0xff) * eteos[base + 1]
               + (float)((pa >> 16) & 0xff) * eteos[base + 2]
               + (float)((pa >> 24) & 0xff) * eteos[base + 3];
            lB = (float)(pb & 0xff)         * eteos[base]
               + (float)((pb >> 8)  & 0xff) * eteos[base + 1]
               + (float)((pb >> 16) & 0xff) * eteos[base + 2]
               + (float)((pb >> 24) & 0xff) * eteos[base + 3];
        }
        lA = wave_sum_f(lA);
        lB = wave_sum_f(lB);
        if (lane == 0) { lz[0][w] = lA; lz[1][w] = lB; }

        // gold scores: threads 0-127 = batch A pos tid; 128-255 = batch B
        int pos = tid & 127;
        int gb  = (tid < 128) ? b0 : b1;
        float mk = mask[gb * Tn + pos];
        float val = 0.f;
        if (pos > 0) {
            int cur  = tags[gb * Tn + pos];
            int prev = tags[gb * Tn + pos - 1];
            val = (em[((size_t)gb * Tn + pos) * S + cur]
                   + trans[prev * S + cur]) * mk;
        }
        float vs = wave_sum_f(val);
        float ms = wave_sum_f(mk);
        if (lane == 0) { redv[w] = vs; redm[w] = ms; }
        __syncthreads();
        if (tid == 0) {
            float totA = lz[0][0] + lz[0][1] + lz[0][2] + lz[0][3];
            float totB = lz[1][0] + lz[1][1] + lz[1][2] + lz[1][3];
            float logzA = csh[0] - KL127 + __logf(totA);
            float logzB = csh[1] - KL127 + __logf(totB);
            float msA = redm[0] + redm[1], msB = redm[2] + redm[3];
            int lastA = (int)(msA + 0.5f) - 1, lastB = (int)(msB + 0.5f) - 1;
            int fA = tags[b0 * Tn], fB = tags[b1 * Tn];
            int lTA = tags[b0 * Tn + lastA], lTB = tags[b1 * Tn + lastB];
            float scoreA = redv[0] + redv[1] + trans[BOSs * S + fA]
                         + em[((size_t)b0 * Tn) * S + fA] + trans[lTA * S + EOSs];
            float scoreB = redv[2] + redv[3] + trans[BOSs * S + fB]
                         + em[((size_t)b1 * Tn) * S + fB] + trans[lTB * S + EOSs];
            atomicAdd(out, -(scoreA - logzA) - (scoreB - logzB));
        }
    }
}

extern "C" void kernel_launch(void* const* d_in, const int* in_sizes, int n_in,
                              void* d_out, int out_size, void* d_ws, size_t ws_size,
                              hipStream_t stream) {
    const float* em    = (const float*)d_in[0];
    const int*   tags  = (const int*)d_in[1];
    const float* mask  = (const float*)d_in[2];
    const float* trans = (const float*)d_in[3];
    float* out = (float*)d_out;

    char* ws = (char*)d_ws;
    size_t off = 0;
    unsigned char* eswz = (unsigned char*)(ws + off);
    off += (size_t)ETOT;
    off = (off + 255) & ~(size_t)255;
    float* eteos = (float*)(ws + off); off += JPAD * sizeof(float);
    off = (off + 255) & ~(size_t)255;
    u64* xb = (u64*)(ws + off);        off += (size_t)2 * Bn * XSTR * sizeof(u64);

    // ws re-poisoned 0xAA pre-launch: poison tag16 = 0xAAAA never matches
    // TAGB|t (high byte 0x5A) -> stale mailbox words can't be consumed.
    (void)hipMemsetAsync(out, 0, sizeof(float), stream);

    build_tabs<<<(ETOT + 255) / 256, 256, 0, stream>>>(trans, eswz, eteos);
    crf_fwd<<<dim3(JB, Bn / 2), 256, 0, stream>>>(em, mask, trans, tags, eswz,
                                                  eteos, xb, out);
}

// Round 15
// 416.572 us; speedup vs baseline: 1.1536x; 1.1536x over previous
//
#include <hip/hip_runtime.h>
#include <math.h>

typedef unsigned long long u64;

static constexpr int S    = 771;   // NB_LABELS*MAX_DEPTH + EXTRA
static constexpr int Tn   = 128;
static constexpr int Bn   = 32;
static constexpr int BOSs = 0;
static constexpr int EOSs = 1;

static constexpr int JPAD  = 832;          // 13 * 64 state pad
static constexpr int JB    = 13;           // state-blocks per batch
static constexpr int NQ    = 4;            // waves per block
static constexpr int CH    = 13;           // uint4 per lane slice (208 i8)
static constexpr int EBLK  = NQ * CH * 64 * 16;      // 53248 B per jblk
static constexpr int ETOT  = JB * EBLK;              // 692224 B
static constexpr int WORDS = 208;          // u64 mailbox words per (parity,batch)
static constexpr int XSTR  = 256;          // padded stride (u64)
static constexpr unsigned TAGB = 0x5A00u;  // tag16 = 0x5A00|t; poison = 0xAAAA
static constexpr float CB  = 8.0f;         // normalizer headroom (drift bound)
static constexpr float C0V = 4.5f;         // fixed normalizer for t=0 publish

__device__ __forceinline__ float wave_max_bfly(float v) {   // result in ALL lanes
    #pragma unroll
    for (int off = 32; off > 0; off >>= 1) v = fmaxf(v, __shfl_xor(v, off));
    return v;
}
__device__ __forceinline__ float wave_sum_f(float v) {
    #pragma unroll
    for (int off = 32; off > 0; off >>= 1) v += __shfl_down(v, off);
    return v;
}

union HU16 { _Float16 h; unsigned short u; };

// MALL-scope (agent atomic) exchange: the r4-r14 replay-proven protocol.
__device__ __forceinline__ u64 ald64(const u64* p) {
    return __hip_atomic_load((u64*)p, __ATOMIC_RELAXED, __HIP_MEMORY_SCOPE_AGENT);
}
__device__ __forceinline__ void ast64(u64* p, u64 v) {
    __hip_atomic_store(p, v, __ATOMIC_RELAXED, __HIP_MEMORY_SCOPE_AGENT);
}

// i8 x i8 + i32 dot (both operands in [0,127], so signed == unsigned)
#if __has_builtin(__builtin_amdgcn_sdot4)
__device__ __forceinline__ int dot4i(unsigned a, unsigned b, int c) {
    return __builtin_amdgcn_sdot4((int)a, (int)b, c, false);
}
#else
__device__ __forceinline__ int dot4i(unsigned a, unsigned b, int c) {
    c += (int)(a & 0xff)         * (int)(b & 0xff);
    c += (int)((a >> 8) & 0xff)  * (int)((b >> 8) & 0xff);
    c += (int)((a >> 16) & 0xff) * (int)((b >> 16) & 0xff);
    c += (int)((a >> 24) & 0xff) * (int)((b >> 24) & 0xff);
    return c;
}
#endif

// ---------------------------------------------------------------------------
// Prep: i8 exp-transition table, swizzled for the r15 per-wave-rows layout:
// eswz[(((jblk*4+w)*13+kk)*64+lane)*16+e] = round(115*exp(trans[i][j])),
//   q = lane>>4, r = lane&15, i = q*208 + kk*16 + e (inner),
//   j = jblk*64 + w*16 + r (output row).
// Plus exp(trans[:,EOS]) f32 column.
// ---------------------------------------------------------------------------
extern "C" __global__ void build_tabs(const float* __restrict__ trans,
                                      unsigned char* __restrict__ eswz,
                                      float* __restrict__ eteos) {
    int idx = blockIdx.x * blockDim.x + threadIdx.x;
    if (idx < JPAD)
        eteos[idx] = (idx < S) ? __expf(trans[idx * S + EOSs]) : 0.f;
    if (idx >= ETOT) return;
    int e = idx & 15;
    int t = idx >> 4;
    int lane = t & 63;  t >>= 6;
    int kk = t % 13;
    int h  = t / 13;
    int w  = h & 3, jblk = h >> 2;
    int q = lane >> 4, r = lane & 15;
    int i = q * 208 + kk * 16 + e;
    int j = jblk * 64 + w * 16 + r;
    float v = 0.f;
    if (i < S && j < S) v = 115.f * __expf(trans[i * S + j]);
    int q8 = (int)(v + 0.5f);
    if (q8 > 127) q8 = 127;
    eswz[idx] = (unsigned char)q8;
}

// publish: wave holds af for its 16 rows in lanes 0..15 (row j0+16w+r).
// Emits 4 tagged u64: word m = [tag16 | wave16rowmax_f16 | p8 of rows 4m..4m+3],
// p8 = round(127*exp(af-C)). Global mailbox word index = (jblk*4+w)*4+m, and
// rows of word W are exactly 4W..4W+3 (row-linear across the batch).
__device__ __forceinline__ void publish(u64* base, unsigned tg, float af,
                                        float C, int lane) {
    float xf = fminf(127.f, 127.f * __expf(af - C));   // -inf/-1e9 -> 0
    int xi = (int)(xf + 0.5f);
    float m = (lane < 16) ? af : -INFINITY;
    m = wave_max_bfly(m);                              // wave's 16-row max
    int c0 = __shfl(xi, (4 * lane) & 63);
    int c1 = __shfl(xi, (4 * lane + 1) & 63);
    int c2 = __shfl(xi, (4 * lane + 2) & 63);
    int c3 = __shfl(xi, (4 * lane + 3) & 63);
    unsigned payload = (unsigned)c0 | ((unsigned)c1 << 8)
                     | ((unsigned)c2 << 16) | ((unsigned)c3 << 24);
    HU16 hh; hh.h = (_Float16)m;
    u64 v = ((u64)tg << 48) | ((u64)hh.u << 32) | (u64)payload;
    if (lane < 4) ast64(base + lane, v);
}

// ---------------------------------------------------------------------------
// Forward algorithm, r15: BARRIER-FREE per-wave gangs.
// r10's 6240 cy/step = sync(~4000) + compute(~2200), and the compute tail
// (cross-wave part combine + barrier + single-wave epilogue) sits on every
// serial chain; the barrier's mandatory vmcnt(0) drain also defeats any
// prefetch (r14). Fix: each wave owns 16 COMPLETE rows (lane (q,r): row
// 16w+r, inner quarter q). Waves independently poll all 208 words (3-4 per
// lane, all issued per spin round -> 4 samples/RT), write a wave-private LDS
// strip (same-wave DS order), dot, combine 4 lanes/row with 2 shuffles, and
// lanes 0-15 do log+publish. ZERO __syncthreads in the 127-step loop.
// Publishers = 52/batch, each with a short uniform chain. Normalizer: every
// word embeds its wave's 16-row max; every wave samples every word -> wave
// max == global max, identical C chain in all waves by induction.
// Buffer-reuse safety: wave-granular transitivity (a wave publishing gen t
// detected ALL waves' gen t-1 => all waves finished consuming gen t-2).
// ---------------------------------------------------------------------------
extern "C" __global__ __launch_bounds__(256, 2)
void crf_fwd(const float* __restrict__ em, const float* __restrict__ mask,
             const float* __restrict__ trans, const int* __restrict__ tags,
             const unsigned char* __restrict__ eswz,
             const float* __restrict__ eteos,
             u64* __restrict__ xb, float* __restrict__ out) {
    const int jblk = blockIdx.x, b = blockIdx.y;
    const int tid = threadIdx.x, lane = tid & 63, w = tid >> 6;
    const int j0 = jblk * 64;
    const int q = lane >> 4;                 // inner quarter of this lane
    const int myrow = j0 + w * 16 + lane;    // valid for lane < 16

    __shared__ __align__(16) unsigned char Elds[EBLK];  // 52 KB i8 E tile
    __shared__ __align__(16) unsigned pstr[NQ][WORDS];  // wave-private strips
    __shared__ float cshare;
    __shared__ float lzred[4];
    __shared__ float redv[4], redm[4];

    const float KLOG  = __logf(115.f * 127.f);
    const float KL127 = __logf(127.f);

    // ---- one-time: stage this block's E tile (13 x 4KB linear copy) ----
    {
        const unsigned char* gsrc = eswz + (size_t)jblk * EBLK;
        #pragma unroll
        for (int it = 0; it < EBLK / 4096; ++it)
            *(float4*)(Elds + it * 4096 + tid * 16) =
                *(const float4*)(gsrc + it * 4096 + tid * 16);
    }

    // per-wave state: af of own 16 rows (lanes 0-15) + normalizer chain
    float af = -INFINITY, Cuse = C0V;
    if (lane < 16 && myrow < S)
        af = trans[BOSs * S + myrow] + em[((size_t)b * Tn + 0) * S + myrow];
    publish(xb + ((size_t)0 * Bn + b) * XSTR + (jblk * NQ + w) * 4,
            TAGB | 0u, af, C0V, lane);

    const bool k3 = (lane < WORDS - 192);    // lanes 0..15 poll a 4th word

    // ---- 127 sequential steps, no barriers ----
    for (int t = 1; t < Tn; ++t) {
        const u64* R = xb + ((size_t)((t - 1) & 1) * Bn + b) * XSTR;
        u64*       W = xb + ((size_t)((t    ) & 1) * Bn + b) * XSTR
                          + (jblk * NQ + w) * 4;

        // epilogue operands independent of alpha: issue before the spin
        float emv = 0.f;
        if (lane < 16 && myrow < S)
            emv = em[((size_t)b * Tn + t) * S + myrow];
        const float mval = mask[b * Tn + t];

        // ---- poll all 208 words: 3-4 per lane, all issued per round ----
        const unsigned tg = TAGB | (unsigned)(t - 1);
        u64 q0 = 0, q1 = 0, q2 = 0, q3 = 0;
        bool o0 = false, o1 = false, o2 = false, o3 = !k3;
        do {
            if (!o0) { q0 = ald64(R + lane);       o0 = ((unsigned)(q0 >> 48) == tg); }
            if (!o1) { q1 = ald64(R + lane + 64);  o1 = ((unsigned)(q1 >> 48) == tg); }
            if (!o2) { q2 = ald64(R + lane + 128); o2 = ((unsigned)(q2 >> 48) == tg); }
            if (!o3) { q3 = ald64(R + lane + 192); o3 = ((unsigned)(q3 >> 48) == tg); }
        } while (__any((!o0) | (!o1) | (!o2) | (!o3)));

        // ---- strip to wave-private LDS (same-wave write->read, no barrier)
        pstr[w][lane]       = (unsigned)q0;
        pstr[w][lane + 64]  = (unsigned)q1;
        pstr[w][lane + 128] = (unsigned)q2;
        if (k3) pstr[w][lane + 192] = (unsigned)q3;

        // ---- normalizer: max over all sampled embedded maxes (global) ----
        HU16 h0, h1, h2, h3;
        h0.u = (unsigned short)(q0 >> 32);
        h1.u = (unsigned short)(q1 >> 32);
        h2.u = (unsigned short)(q2 >> 32);
        h3.u = (unsigned short)(q3 >> 32);
        float mx = fmaxf(fmaxf((float)h0.h, (float)h1.h), (float)h2.h);
        if (k3) mx = fmaxf(mx, (float)h3.h);
        const float Cnew = wave_max_bfly(mx) + CB;

        // ---- dot: lane (q,r) = row 16w+r x inner quarter q ----
        int acc = 0;
        const uint4* E4 = (const uint4*)Elds;
        const uint4* P4 = (const uint4*)&pstr[w][52 * q];
        #pragma unroll
        for (int kk = 0; kk < CH; ++kk) {
            const uint4 ev = E4[(w * CH + kk) * 64 + lane];
            const uint4 pv = P4[kk];
            acc = dot4i(ev.x, pv.x, acc); acc = dot4i(ev.y, pv.y, acc);
            acc = dot4i(ev.z, pv.z, acc); acc = dot4i(ev.w, pv.w, acc);
        }
        // combine the 4 quarter-partials of each row (lanes r,r+16,r+32,r+48)
        acc += __shfl_down(acc, 32);
        acc += __shfl_down(acc, 16);

        // ---- epilogue (lanes 0-15): alpha' = Cuse - KLOG + log(acc) + em
        if (lane < 16) {
            float nv = Cuse - KLOG + __logf((float)acc) + emv; // log(0) = -inf
            af = (mval > 0.f) ? nv : af;
        }
        publish(W, TAGB | (unsigned)t, af, Cnew, lane);
        Cuse = Cnew;
    }

    // ---- tail (blocks jblk==0): log_Z + gold score + output ----
    if (jblk == 0) {
        if (tid == 0) cshare = Cuse;     // identical in all waves
        const u64* R = xb + ((size_t)((Tn - 1) & 1) * Bn + b) * XSTR;
        const unsigned tgf = TAGB | (unsigned)(Tn - 1);
        const bool act = (tid < WORDS);
        u64 qf = 0;
        bool ok = !act;
        while (true) {
            if (!ok) { qf = ald64(R + tid); ok = ((unsigned)(qf >> 48) == tgf); }
            if (__syncthreads_and(ok)) break;
        }
        float lsum = 0.f;
        if (act) {                        // word tid covers rows 4*tid..+3
            unsigned pv = (unsigned)qf;
            int base = 4 * tid;
            lsum = (float)(pv & 0xff)         * eteos[base]
                 + (float)((pv >> 8)  & 0xff) * eteos[base + 1]
                 + (float)((pv >> 16) & 0xff) * eteos[base + 2]
                 + (float)((pv >> 24) & 0xff) * eteos[base + 3];
        }
        // gold-path score (exact fp32: carries the -1e9 forbidden terms)
        float mk = 0.f, val = 0.f;
        if (tid < Tn) {
            mk = mask[b * Tn + tid];
            if (tid > 0) {
                int cur  = tags[b * Tn + tid];
                int prev = tags[b * Tn + tid - 1];
                val = (em[((size_t)b * Tn + tid) * S + cur]
                       + trans[prev * S + cur]) * mk;
            }
        }
        lsum = wave_sum_f(lsum);
        float vs = wave_sum_f(val);
        float ms = wave_sum_f(mk);
        if (lane == 0) { redv[w] = vs; redm[w] = ms; lzred[w] = lsum; }
        __syncthreads();
        if (tid == 0) {
            float tot  = lzred[0] + lzred[1] + lzred[2] + lzred[3];
            float logz = cshare - KL127 + __logf(tot);
            float msum = redm[0] + redm[1] + redm[2] + redm[3];
            int last   = (int)(msum + 0.5f) - 1;
            int first  = tags[b * Tn];
            int lastt  = tags[b * Tn + last];
            float score = redv[0] + redv[1] + redv[2] + redv[3]
                        + trans[BOSs * S + first]
                        + em[((size_t)b * Tn) * S + first]
                        + trans[lastt * S + EOSs];
            atomicAdd(out, -(score - logz));
        }
    }
}

extern "C" void kernel_launch(void* const* d_in, const int* in_sizes, int n_in,
                              void* d_out, int out_size, void* d_ws, size_t ws_size,
                              hipStream_t stream) {
    const float* em    = (const float*)d_in[0];
    const int*   tags  = (const int*)d_in[1];
    const float* mask  = (const float*)d_in[2];
    const float* trans = (const float*)d_in[3];
    float* out = (float*)d_out;

    char* ws = (char*)d_ws;
    size_t off = 0;
    unsigned char* eswz = (unsigned char*)(ws + off);
    off += (size_t)ETOT;
    off = (off + 255) & ~(size_t)255;
    float* eteos = (float*)(ws + off); off += JPAD * sizeof(float);
    off = (off + 255) & ~(size_t)255;
    u64* xb = (u64*)(ws + off);        off += (size_t)2 * Bn * XSTR * sizeof(u64);

    // ws re-poisoned 0xAA pre-launch: poison tag16 = 0xAAAA never matches
    // TAGB|t (high byte 0x5A) -> stale mailbox words can't be consumed.
    (void)hipMemsetAsync(out, 0, sizeof(float), stream);

    build_tabs<<<(ETOT + 255) / 256, 256, 0, stream>>>(trans, eswz, eteos);
    crf_fwd<<<dim3(JB, Bn), 256, 0, stream>>>(em, mask, trans, tags, eswz,
                                              eteos, xb, out);
}

// Round 16
// 391.925 us; speedup vs baseline: 1.2262x; 1.0629x over previous
//
#include <hip/hip_runtime.h>
#include <math.h>

typedef unsigned long long u64;

static constexpr int S    = 771;   // NB_LABELS*MAX_DEPTH + EXTRA
static constexpr int Tn   = 128;
static constexpr int Bn   = 32;
static constexpr int BOSs = 0;
static constexpr int EOSs = 1;

static constexpr int JPAD  = 832;          // 13 * 64 state pad
static constexpr int JB    = 13;           // state-blocks per batch
static constexpr int ROWS  = 64;           // output rows per block (= lanes)
static constexpr int NQ    = 4;            // waves per block
static constexpr int SL    = JPAD / NQ;    // 208 i8 inner slice per thread
static constexpr int CH    = SL / 16;      // 13 x b128 per thread
static constexpr int EBLK  = NQ * CH * ROWS * 16;    // 53248 B per jblk
static constexpr int ETOT  = JB * EBLK;              // 692224 B
static constexpr int XSTR  = 224;          // padded stride (u64) per (parity,batch)
static constexpr float CB  = 8.0f;         // normalizer headroom (drift bound)
static constexpr float C0V = 4.5f;         // fixed normalizer for t=0 publish

// ---------------------------------------------------------------------------
// r16 = r10 verbatim (the session's measured optimum: 330 us kernel, 391 us
// total). r11-r15 falsified every structural alternative: XCD-local sc0
// exchange (r12, ~530), 2-batch pipelining (r13, 371), poll prefetch (r14,
// 419), barrier-free per-wave gangs (r15, 358), 1-block/CU (r9, 364).
// The floor is 127 serial MALL exchanges x ~5300 cy (visibility + detect
// quantization + 13-publisher straggler max), not a counter-visible pipe.
// ---------------------------------------------------------------------------

__device__ __forceinline__ float wave_max_bfly(float v) {   // result in ALL lanes
    #pragma unroll
    for (int off = 32; off > 0; off >>= 1) v = fmaxf(v, __shfl_xor(v, off));
    return v;
}
__device__ __forceinline__ float wave_sum_f(float v) {
    #pragma unroll
    for (int off = 32; off > 0; off >>= 1) v += __shfl_down(v, off);
    return v;
}

__device__ __forceinline__ u64 ald64(const u64* p) {
    return __hip_atomic_load((u64*)p, __ATOMIC_RELAXED, __HIP_MEMORY_SCOPE_AGENT);
}
__device__ __forceinline__ void ast64(u64* p, u64 v) {
    __hip_atomic_store(p, v, __ATOMIC_RELAXED, __HIP_MEMORY_SCOPE_AGENT);
}
__device__ __forceinline__ u64 pack(unsigned tag, unsigned payload) {
    return ((u64)tag << 32) | (u64)payload;
}

// i8 x i8 + i32 dot (both operands in [0,127], so signed == unsigned)
#if __has_builtin(__builtin_amdgcn_sdot4)
__device__ __forceinline__ int dot4i(unsigned a, unsigned b, int c) {
    return __builtin_amdgcn_sdot4((int)a, (int)b, c, false);
}
#else
__device__ __forceinline__ int dot4i(unsigned a, unsigned b, int c) {
    c += (int)(a & 0xff)         * (int)(b & 0xff);
    c += (int)((a >> 8) & 0xff)  * (int)((b >> 8) & 0xff);
    c += (int)((a >> 16) & 0xff) * (int)((b >> 16) & 0xff);
    c += (int)((a >> 24) & 0xff) * (int)((b >> 24) & 0xff);
    return c;
}
#endif

// ---------------------------------------------------------------------------
// Prep: i8 exp-transition table (swizzled) + exp(trans[:,EOS]) f32 column.
// eswz[jblk][q][kk][lane][16] = round(115*exp(trans[i][j])) in [0,127],
//   i = q*208 + kk*16 + e (inner), j = jblk*64 + lane (output row).
// exp(-1e9)*115 -> 0: forbidden transitions vanish from the integer dots.
// ---------------------------------------------------------------------------
extern "C" __global__ void build_tabs(const float* __restrict__ trans,
                                      unsigned char* __restrict__ eswz,
                                      float* __restrict__ eteos) {
    int idx = blockIdx.x * blockDim.x + threadIdx.x;
    if (idx < JPAD)
        eteos[idx] = (idx < S) ? __expf(trans[idx * S + EOSs]) : 0.f;
    if (idx >= ETOT) return;
    int e = idx & 15;
    int q = idx >> 4;
    int lane = q & 63;  q >>= 6;
    int kk = q % 13;
    int h  = q / 13;
    int w  = h & 3, jblk = h >> 2;
    int i = w * SL + kk * 16 + e;
    int j = jblk * ROWS + lane;
    float v = 0.f;
    if (i < S && j < S) v = 115.f * __expf(trans[i * S + j]);
    int q8 = (int)(v + 0.5f);
    if (q8 > 127) q8 = 127;
    eswz[idx] = (unsigned char)q8;
}

// publish (wave 0): 64 rows -> p8 = round(127*exp(alpha-C)) packed 4/u64
// (16 u64) + 1 u64 f32 chunk max. Tag stream IS the sync.
__device__ __forceinline__ void publish(u64* W, int jblk, unsigned tag,
                                        float af, float C, int lane) {
    float xf = fminf(127.f, 127.f * __expf(af - C));   // -inf/-1e9 -> 0
    int xi = (int)(xf + 0.5f);
    int b0 = __shfl(xi, (4 * lane) & 63);
    int b1 = __shfl(xi, (4 * lane + 1) & 63);
    int b2 = __shfl(xi, (4 * lane + 2) & 63);
    int b3 = __shfl(xi, (4 * lane + 3) & 63);
    unsigned payload = (unsigned)b0 | ((unsigned)b1 << 8)
                     | ((unsigned)b2 << 16) | ((unsigned)b3 << 24);
    float mc = wave_max_bfly(af);
    u64* base = W + 17 * jblk;
    if (lane < 16)  ast64(base + lane, pack(tag, payload));
    if (lane == 16) ast64(base + 16,   pack(tag, __float_as_uint(mc)));
}

// ---------------------------------------------------------------------------
// Forward algorithm (r10 structure): per-wave dataflow sync. Wave w's
// K-quarter needs only publishers bw..bw+3 (bw = 13w/4): one data u64 per
// lane, wave-level __any spin, no block barrier in the poll loop. Each wave
// writes its 52 u32 to a private LDS strip and reads it back same-wave (DS
// ordering). ONE __syncthreads per step (part combine, double-buffered by
// t&1). Wave 0 additionally polls the 13 chunk maxes for the normalizer.
// Buffer-reuse safety: a block publishes gen t+1 only after all 4 waves
// (covering all 13 publishers) passed this step's poll + barrier =>
// transitively every block consumed gen t-1 before its parity slot reuse.
// ---------------------------------------------------------------------------
extern "C" __global__ __launch_bounds__(256, 2)
void crf_fwd(const float* __restrict__ em, const float* __restrict__ mask,
             const float* __restrict__ trans, const int* __restrict__ tags,
             const unsigned char* __restrict__ eswz,
             const float* __restrict__ eteos,
             u64* __restrict__ xb, float* __restrict__ out) {
    const int jblk = blockIdx.x, b = blockIdx.y;
    const int tid = threadIdx.x, lane = tid & 63, w = tid >> 6;
    const int j0 = jblk * ROWS;
    const int bw = (13 * w) / 4;             // first publisher of my K-quarter
    const int lo = 52 * w - 16 * bw;         // lane offset of my strip

    __shared__ __align__(16) unsigned char Elds[EBLK];  // 52 KB i8 E tile
    __shared__ __align__(16) unsigned pq[NQ][SL / 4];   // per-wave 52-u32 strip
    __shared__ int   part[2][NQ][ROWS];
    __shared__ float cshare;
    __shared__ float redv[4], redm[4];

    const float KLOG  = __logf(115.f * 127.f);
    const float KL127 = __logf(127.f);

    // ---- one-time: stage this block's E tile (13 x 4KB linear copy) ----
    {
        const unsigned char* gsrc = eswz + (size_t)jblk * EBLK;
        #pragma unroll
        for (int it = 0; it < EBLK / 4096; ++it)
            *(float4*)(Elds + it * 4096 + tid * 16) =
                *(const float4*)(gsrc + it * 4096 + tid * 16);
    }

    // wave-0 per-lane state: alpha of own row + normalizer of consumed gen
    float af = -INFINITY, Cuse = C0V;
    if (w == 0) {
        int j = j0 + lane;
        if (j < S) af = trans[BOSs * S + j] + em[((size_t)b * Tn + 0) * S + j];
        publish(xb + ((size_t)0 * Bn + b) * XSTR, jblk, 0u, af, C0V, lane);
    }

    const bool pollmax = (w == 0) && (lane < JB);

    // ---- 127 sequential steps ----
    for (int t = 1; t < Tn; ++t) {
        const u64* R = xb + ((size_t)((t - 1) & 1) * Bn + b) * XSTR;
        u64*       W = xb + ((size_t)((t    ) & 1) * Bn + b) * XSTR;

        // epilogue operands independent of alpha: issue before the poll
        float emv = 0.f, mval = 0.f;
        if (w == 0) {
            const int j = j0 + lane;
            if (j < S) emv = em[((size_t)b * Tn + t) * S + j];
            mval = mask[b * Tn + t];
        }

        // ---- per-wave poll: one data u64/lane (+ maxes on wave 0) ----
        const unsigned tg = (unsigned)(t - 1);
        const u64* pd = R + 17 * (bw + (lane >> 4)) + (lane & 15);
        const u64* pm = R + 17 * lane + 16;
        u64 qd = 0, qm = 0;
        bool okd = false, okm = !pollmax;
        do {
            if (!okd) { qd = ald64(pd); okd = ((unsigned)(qd >> 32) == tg); }
            if (!okm) { qm = ald64(pm); okm = ((unsigned)(qm >> 32) == tg); }
        } while (__any((!okd) | (!okm)));

        // ---- unpack own strip (same-wave write->read: DS order, no barrier)
        if (lane >= lo && lane < lo + 52) pq[w][lane - lo] = (unsigned)qd;

        // wave 0: next normalizer from the 13 chunk maxes
        float Cnew = 0.f;
        if (w == 0) {
            float mv = (lane < JB) ? __uint_as_float((unsigned)qm) : -INFINITY;
            Cnew = wave_max_bfly(mv) + CB;
        }

        // ---- dot: LDS i8 E (b128) x own strip (b128 broadcast) ----
        int acc = 0;
        const uint4* E4 = (const uint4*)Elds;
        const uint4* P4 = (const uint4*)pq[w];
        #pragma unroll
        for (int kk = 0; kk < CH; ++kk) {
            const uint4 ev = E4[(w * CH + kk) * 64 + lane];
            const uint4 pv = P4[kk];
            acc = dot4i(ev.x, pv.x, acc);
            acc = dot4i(ev.y, pv.y, acc);
            acc = dot4i(ev.z, pv.z, acc);
            acc = dot4i(ev.w, pv.w, acc);
        }
        part[t & 1][w][lane] = acc;
        __syncthreads();   // the ONLY per-step barrier

        // ---- epilogue (wave 0): combine, log, publish gen t ----
        if (w == 0) {
            int s4 = part[t & 1][0][lane] + part[t & 1][1][lane]
                   + part[t & 1][2][lane] + part[t & 1][3][lane];
            float nv = Cuse - KLOG + __logf((float)s4) + emv;  // log(0) = -inf
            af = (mval > 0.f) ? nv : af;
            publish(W, jblk, (unsigned)t, af, Cnew, lane);
            if (lane == 0) cshare = Cnew;
            Cuse = Cnew;
        }
    }

    // ---- tail (block jblk==0 only): log_Z + gold score + output ----
    if (jblk == 0) {
        const u64* R = xb + ((size_t)((Tn - 1) & 1) * Bn + b) * XSTR;
        const unsigned tg = (unsigned)(Tn - 1);
        const bool act = (tid < JB * 16);
        u64 q = 0;
        bool ok = !act;
        while (true) {
            if (!ok) {
                q = ald64(R + 17 * (tid >> 4) + (tid & 15));
                ok = ((unsigned)(q >> 32) == tg);
            }
            if (__syncthreads_and(ok)) break;
        }
        float lsum = 0.f;
        if (act) {
            unsigned pv = (unsigned)q;
            int base = 4 * tid;                 // p8 index = (j*64 + s*4)
            lsum = (float)(pv & 0xff)         * eteos[base]
                 + (float)((pv >> 8)  & 0xff) * eteos[base + 1]
                 + (float)((pv >> 16) & 0xff) * eteos[base + 2]
                 + (float)((pv >> 24) & 0xff) * eteos[base + 3];
        }
        // gold-path score (exact fp32: carries the -1e9 forbidden terms)
        float mk = 0.f, val = 0.f;
        if (tid < Tn) {
            mk = mask[b * Tn + tid];
            if (tid > 0) {
                int cur  = tags[b * Tn + tid];
                int prev = tags[b * Tn + tid - 1];
                val = (em[((size_t)b * Tn + tid) * S + cur]
                       + trans[prev * S + cur]) * mk;
            }
        }
        lsum = wave_sum_f(lsum);
        float vs = wave_sum_f(val);
        float ms = wave_sum_f(mk);
        if (lane == 0) { redv[w] = vs; redm[w] = ms; part[0][0][w] = 0; }
        if (lane == 1) part[1][0][w] = __float_as_int(lsum);
        __syncthreads();
        if (tid == 0) {
            float tot = __int_as_float(part[1][0][0]) + __int_as_float(part[1][0][1])
                      + __int_as_float(part[1][0][2]) + __int_as_float(part[1][0][3]);
            float logz = cshare - KL127 + __logf(tot);
            float msum = redm[0] + redm[1] + redm[2] + redm[3];
            int last   = (int)(msum + 0.5f) - 1;
            int first  = tags[b * Tn];
            int lastt  = tags[b * Tn + last];
            float score = redv[0] + redv[1] + redv[2] + redv[3]
                        + trans[BOSs * S + first]
                        + em[((size_t)b * Tn) * S + first]
                        + trans[lastt * S + EOSs];
            atomicAdd(out, -(score - logz));
        }
    }
}

extern "C" void kernel_launch(void* const* d_in, const int* in_sizes, int n_in,
                              void* d_out, int out_size, void* d_ws, size_t ws_size,
                              hipStream_t stream) {
    const float* em    = (const float*)d_in[0];
    const int*   tags  = (const int*)d_in[1];
    const float* mask  = (const float*)d_in[2];
    const float* trans = (const float*)d_in[3];
    float* out = (float*)d_out;

    char* ws = (char*)d_ws;
    size_t off = 0;
    unsigned char* eswz = (unsigned char*)(ws + off);
    off += (size_t)ETOT;
    off = (off + 255) & ~(size_t)255;
    float* eteos = (float*)(ws + off); off += JPAD * sizeof(float);
    off = (off + 255) & ~(size_t)255;
    u64* xb = (u64*)(ws + off);        off += (size_t)2 * Bn * XSTR * sizeof(u64);

    // ws re-poisoned 0xAA pre-launch: stale tags (0xAAAAAAAA) never match t<128
    (void)hipMemsetAsync(out, 0, sizeof(float), stream);

    build_tabs<<<(ETOT + 255) / 256, 256, 0, stream>>>(trans, eswz, eteos);
    crf_fwd<<<dim3(JB, Bn), 256, 0, stream>>>(em, mask, trans, tags, eswz,
                                              eteos, xb, out);
}